// Round 2
// baseline (583.024 us; speedup 1.0000x reference)
//
#include <hip/hip_runtime.h>

// Convert2Image: out[b,h,w,:] = lstm[b, slic[b,h,w]-1, :]
// B=4, S=256, C=128, H=W=512. fp32 in/out.
// ~536 MB written (write-once), ~4.5 MB effective reads -> write-BW bound.
//
// R1 changes vs R0 (567 us, ~0.95 TB/s effective):
//  - 4 independent gather chains per thread (was 1) -> 4x memory-level
//    parallelism per wave; the R0 kernel serialized slic->lstm->store with
//    vmcnt(0) between each stage.
//  - __builtin_nontemporal_store for the 512 MiB write-once output and
//    nontemporal load for the stream-once slic: keeps the 512 KiB lstm table
//    L2-resident, avoids polluting L2 with the output stream.

typedef float v4f __attribute__((ext_vector_type(4)));

constexpr int LOG_C4  = 5;    // C/4 = 32 float4 per pixel
constexpr int C4MASK  = 31;
constexpr int LOG_HW  = 18;   // H*W = 262144
constexpr int LOG_S   = 8;    // S = 256

constexpr int UNROLL  = 4;
constexpr int BLOCK   = 256;

__global__ __launch_bounds__(BLOCK)
void convert2image_kernel(const v4f* __restrict__ lstm,  // [B*S*32]
                          const int* __restrict__ slic,  // [B*H*W], 1-based
                          v4f*       __restrict__ out)   // [B*H*W*32]
{
    const int stride = gridDim.x * BLOCK;      // elements between unroll iters
    const int i0 = blockIdx.x * BLOCK + threadIdx.x;

    // Stage 1: 4 independent slic loads (each broadcast across 32 lanes).
    int seg[UNROLL];
#pragma unroll
    for (int k = 0; k < UNROLL; ++k) {
        int i   = i0 + k * stride;
        int pix = i >> LOG_C4;                 // linear pixel over B*H*W
        seg[k]  = __builtin_nontemporal_load(&slic[pix]) - 1;
    }

    // Stage 2: 4 independent gathers from the L2-resident lstm table.
    v4f val[UNROLL];
#pragma unroll
    for (int k = 0; k < UNROLL; ++k) {
        int i  = i0 + k * stride;
        int c4 = i & C4MASK;
        int b  = i >> (LOG_C4 + LOG_HW);       // batch
        val[k] = lstm[(((b << LOG_S) + seg[k]) << LOG_C4) + c4];
    }

    // Stage 3: 4 streaming stores, perfectly coalesced (1 KiB per wave each).
#pragma unroll
    for (int k = 0; k < UNROLL; ++k) {
        __builtin_nontemporal_store(val[k], &out[i0 + k * stride]);
    }
}

extern "C" void kernel_launch(void* const* d_in, const int* in_sizes, int n_in,
                              void* d_out, int out_size, void* d_ws, size_t ws_size,
                              hipStream_t stream) {
    const v4f* lstm = (const v4f*)d_in[0];   // graph_lstm_output [4,256,128] f32
    const int* slic = (const int*)d_in[1];   // slic_output [4,512,512] i32
    v4f*       out  = (v4f*)d_out;           // [4,512,512,128] f32

    int n4 = out_size / 4;                   // 33,554,432 float4 elements (2^25)
    int blocks = n4 / (BLOCK * UNROLL);      // 32768 blocks, exact (2^25 / 2^10)
    convert2image_kernel<<<blocks, BLOCK, 0, stream>>>(lstm, slic, out);
}